// Round 1
// baseline (5149.086 us; speedup 1.0000x reference)
//
#include <hip/hip_runtime.h>

#define N_NODES 100000
#define N_EDGES 1600000
#define F 64

static_assert(N_NODES % 4 == 0, "node groups exact");
static_assert(N_EDGES % 8 == 0, "edge groups exact");

__device__ __forceinline__ float silu_f(float v) {
    return v / (1.0f + __expf(-v));
}

// register broadcast: all lanes read lane l's value (constant l after unroll -> v_readlane_b32)
__device__ __forceinline__ float bcast(float v, int l) {
    return __int_as_float(__builtin_amdgcn_readlane(__float_as_int(v), l));
}

// A = h @ ew1[0:64], B = h @ ew1[64:128]; also zero h_neigh / x_neigh for this layer.
__global__ __launch_bounds__(256) void node_pre(
    const float* __restrict__ h, const float* __restrict__ ew1,
    float* __restrict__ A, float* __restrict__ B,
    float* __restrict__ h_neigh, float* __restrict__ x_neigh)
{
    __shared__ float wA[F * F], wB[F * F];
    const int tid = threadIdx.x;
    #pragma unroll 4
    for (int i = tid; i < F * F; i += 256) { wA[i] = ew1[i]; wB[i] = ew1[F * F + i]; }
    __syncthreads();
    const int lane = tid & 63;
    const int nw = gridDim.x * 4;
    const int wid = blockIdx.x * 4 + (tid >> 6);
    for (int g = wid; g < N_NODES / 4; g += nw) {
        const int n0 = g * 4;
        float hr[4];
        #pragma unroll
        for (int e = 0; e < 4; ++e) hr[e] = h[(n0 + e) * F + lane];
        float aA[4] = {0.f, 0.f, 0.f, 0.f}, aB[4] = {0.f, 0.f, 0.f, 0.f};
        #pragma unroll
        for (int k = 0; k < F; ++k) {
            const float wa = wA[k * F + lane];
            const float wb = wB[k * F + lane];
            #pragma unroll
            for (int e = 0; e < 4; ++e) {
                const float hv = bcast(hr[e], k);
                aA[e] = fmaf(hv, wa, aA[e]);
                aB[e] = fmaf(hv, wb, aB[e]);
            }
        }
        #pragma unroll
        for (int e = 0; e < 4; ++e) {
            A[(n0 + e) * F + lane] = aA[e];
            B[(n0 + e) * F + lane] = aB[e];
            h_neigh[(n0 + e) * F + lane] = 0.0f;
        }
        if (lane < 12) x_neigh[n0 * 3 + lane] = 0.0f;
    }
}

// per-edge MLPs + atomic scatter. 8 edges per wave, feature-per-lane.
__global__ __launch_bounds__(256) void edge_kernel(
    const float* __restrict__ A, const float* __restrict__ B,
    const float* __restrict__ x,
    const int* __restrict__ src, const int* __restrict__ dst,
    const float* __restrict__ rw,  const float* __restrict__ eb1,
    const float* __restrict__ ew2, const float* __restrict__ eb2,
    const float* __restrict__ cw1, const float* __restrict__ cb1,
    const float* __restrict__ cw2,
    float* __restrict__ h_neigh, float* __restrict__ x_neigh)
{
    __shared__ float wE[F * F], wC[F * F];
    const int tid = threadIdx.x;
    #pragma unroll 4
    for (int i = tid; i < F * F; i += 256) { wE[i] = ew2[i]; wC[i] = cw1[i]; }
    __syncthreads();
    const int lane = tid & 63;
    const float rwv = rw[lane], eb1v = eb1[lane], eb2v = eb2[lane];
    const float cb1v = cb1[lane], cw2v = cw2[lane];
    const int eidx = lane / 3;            // lanes 0..23 own (edge, coord) pairs
    const int cc = lane - eidx * 3;
    const int nw = gridDim.x * 4;
    const int wid = blockIdx.x * 4 + (tid >> 6);
    for (int g = wid; g < N_EDGES / 8; g += nw) {
        const int e0 = g * 8;
        int srcs[8], dsts[8];
        #pragma unroll
        for (int e = 0; e < 8; ++e) {
            srcs[e] = __builtin_amdgcn_readfirstlane(src[e0 + e]);
            dsts[e] = __builtin_amdgcn_readfirstlane(dst[e0 + e]);
        }
        // gathers (issue early; coalesced 256B per edge)
        float aA[8], aB[8];
        #pragma unroll
        for (int e = 0; e < 8; ++e) {
            aA[e] = A[srcs[e] * F + lane];
            aB[e] = B[dsts[e] * F + lane];
        }
        // coordinate work: lane = eidx*3+cc handles component cc of edge eidx
        int ms = srcs[0], md = dsts[0];
        #pragma unroll
        for (int e = 1; e < 8; ++e) if (eidx == e) { ms = srcs[e]; md = dsts[e]; }
        float xdv = 0.0f;
        if (lane < 24) xdv = x[ms * 3 + cc] - x[md * 3 + cc];
        const float xx = xdv * xdv;
        const int base3 = eidx * 3;
        const float rad = __shfl(xx, base3, 64) + __shfl(xx, base3 + 1, 64)
                        + __shfl(xx, base3 + 2, 64);
        const float xdn = xdv / (sqrtf(rad) + 1e-30f);   // normalized diff (lanes<24)
        // m1 = silu(A[src] + B[dst] + radial*ew1_row128 + eb1)
        float m1[8];
        #pragma unroll
        for (int e = 0; e < 8; ++e) {
            const float rv = bcast(rad, e * 3);
            m1[e] = silu_f(aA[e] + aB[e] + rv * rwv + eb1v);
        }
        // m = silu(m1 @ ew2 + eb2)
        float acc[8] = {0, 0, 0, 0, 0, 0, 0, 0};
        #pragma unroll
        for (int k = 0; k < F; ++k) {
            const float wv = wE[k * F + lane];
            #pragma unroll
            for (int e = 0; e < 8; ++e)
                acc[e] = fmaf(bcast(m1[e], k), wv, acc[e]);
        }
        float m[8];
        #pragma unroll
        for (int e = 0; e < 8; ++e) m[e] = silu_f(acc[e] + eb2v);
        // c1 = silu(m @ cw1 + cb1); partial dot with cw2
        float acc2[8] = {0, 0, 0, 0, 0, 0, 0, 0};
        #pragma unroll
        for (int k = 0; k < F; ++k) {
            const float wv = wC[k * F + lane];
            #pragma unroll
            for (int e = 0; e < 8; ++e)
                acc2[e] = fmaf(bcast(m[e], k), wv, acc2[e]);
        }
        float part[8];
        #pragma unroll
        for (int e = 0; e < 8; ++e) part[e] = silu_f(acc2[e] + cb1v) * cw2v;
        // butterfly reduce each edge's scalar c over 64 lanes (all lanes end with total)
        #pragma unroll
        for (int e = 0; e < 8; ++e) {
            float v = part[e];
            v += __shfl_xor(v, 32, 64);
            v += __shfl_xor(v, 16, 64);
            v += __shfl_xor(v,  8, 64);
            v += __shfl_xor(v,  4, 64);
            v += __shfl_xor(v,  2, 64);
            v += __shfl_xor(v,  1, 64);
            part[e] = v;
        }
        // scatter h message (coalesced 64-lane atomics per edge)
        #pragma unroll
        for (int e = 0; e < 8; ++e)
            atomicAdd(&h_neigh[dsts[e] * F + lane], m[e]);
        // scatter coord message (lanes 0..23: 3 components x 8 edges)
        if (lane < 24) {
            float ct = part[0];
            #pragma unroll
            for (int e = 1; e < 8; ++e) if (eidx == e) ct = part[e];
            atomicAdd(&x_neigh[md * 3 + cc], ct * xdn);
        }
    }
}

// h_new = silu([h,h_neigh] @ nw1 + nb1) @ nw2 + nb2;  x_new = x + x_neigh
__global__ __launch_bounds__(256) void node_post(
    const float* __restrict__ h, const float* __restrict__ hng,
    const float* __restrict__ nw1, const float* __restrict__ nb1,
    const float* __restrict__ nw2, const float* __restrict__ nb2,
    const float* __restrict__ x_in, const float* __restrict__ xng,
    float* __restrict__ h_out, float* __restrict__ x_out)
{
    __shared__ float w1a[F * F], w1b[F * F], w2[F * F];
    const int tid = threadIdx.x;
    #pragma unroll 4
    for (int i = tid; i < F * F; i += 256) {
        w1a[i] = nw1[i]; w1b[i] = nw1[F * F + i]; w2[i] = nw2[i];
    }
    __syncthreads();
    const int lane = tid & 63;
    const float b1 = nb1[lane], b2 = nb2[lane];
    const int nw = gridDim.x * 4;
    const int wid = blockIdx.x * 4 + (tid >> 6);
    for (int g = wid; g < N_NODES / 4; g += nw) {
        const int n0 = g * 4;
        float hr[4], gr[4];
        #pragma unroll
        for (int e = 0; e < 4; ++e) {
            hr[e] = h[(n0 + e) * F + lane];
            gr[e] = hng[(n0 + e) * F + lane];
        }
        float t[4] = {b1, b1, b1, b1};
        #pragma unroll
        for (int k = 0; k < F; ++k) {
            const float wa = w1a[k * F + lane];
            const float wb = w1b[k * F + lane];
            #pragma unroll
            for (int e = 0; e < 4; ++e) {
                t[e] = fmaf(bcast(hr[e], k), wa, t[e]);
                t[e] = fmaf(bcast(gr[e], k), wb, t[e]);
            }
        }
        #pragma unroll
        for (int e = 0; e < 4; ++e) t[e] = silu_f(t[e]);
        float o[4] = {b2, b2, b2, b2};
        #pragma unroll
        for (int k = 0; k < F; ++k) {
            const float wv = w2[k * F + lane];
            #pragma unroll
            for (int e = 0; e < 4; ++e)
                o[e] = fmaf(bcast(t[e], k), wv, o[e]);
        }
        #pragma unroll
        for (int e = 0; e < 4; ++e) h_out[(n0 + e) * F + lane] = o[e];
        if (lane < 12) x_out[n0 * 3 + lane] = x_in[n0 * 3 + lane] + xng[n0 * 3 + lane];
    }
}

extern "C" void kernel_launch(void* const* d_in, const int* in_sizes, int n_in,
                              void* d_out, int out_size, void* d_ws, size_t ws_size,
                              hipStream_t stream) {
    const float* h_in0 = (const float*)d_in[0];
    const float* x_in0 = (const float*)d_in[1];
    const int*   src   = (const int*)d_in[2];
    const int*   dst   = (const int*)d_in[3];
    const float* ew1   = (const float*)d_in[4];
    const float* eb1   = (const float*)d_in[5];
    const float* ew2   = (const float*)d_in[6];
    const float* eb2   = (const float*)d_in[7];
    const float* nw1   = (const float*)d_in[8];
    const float* nb1   = (const float*)d_in[9];
    const float* nw2   = (const float*)d_in[10];
    const float* nb2   = (const float*)d_in[11];
    const float* cw1   = (const float*)d_in[12];
    const float* cb1   = (const float*)d_in[13];
    const float* cw2   = (const float*)d_in[14];
    float* out = (float*)d_out;

    const size_t NF = (size_t)N_NODES * F;
    float* A   = (float*)d_ws;       // [N,64]
    float* B   = A + NF;             // [N,64]
    float* hng = B + NF;             // h_neigh [N,64]
    float* h0  = hng + NF;           // h ping  [N,64]
    float* h1  = h0 + NF;            // h pong  [N,64]
    float* xw  = h1 + NF;            // x       [N,3]
    float* xng = xw + (size_t)N_NODES * 3;  // x_neigh [N,3]

    for (int d = 0; d < 4; ++d) {
        const float* hcur = (d == 0) ? h_in0 : ((d & 1) ? h0 : h1);
        float* hout = (d & 1) ? h1 : h0;
        const float* xcur = (d == 0) ? x_in0 : xw;
        float* xout = (d == 3) ? out : xw;
        node_pre<<<1024, 256, 0, stream>>>(hcur, ew1 + (size_t)d * 129 * F,
                                           A, B, hng, xng);
        edge_kernel<<<1280, 256, 0, stream>>>(A, B, xcur, src, dst,
            ew1 + (size_t)d * 129 * F + 128 * F, eb1 + d * F,
            ew2 + (size_t)d * F * F, eb2 + d * F,
            cw1 + (size_t)d * F * F, cb1 + d * F, cw2 + d * F,
            hng, xng);
        node_post<<<768, 256, 0, stream>>>(hcur, hng,
            nw1 + (size_t)d * 2 * F * F, nb1 + d * F,
            nw2 + (size_t)d * F * F, nb2 + d * F,
            xcur, xng, hout, xout);
    }
}

// Round 3
// 2906.279 us; speedup vs baseline: 1.7717x; 1.7717x over previous
//
#include <hip/hip_runtime.h>

#define N_NODES 100000
#define N_EDGES 1600000
#define F 64

static_assert(N_NODES % 4 == 0, "node groups exact");
static_assert(N_EDGES % 16 == 0, "edge groups exact");

using short8 = __attribute__((ext_vector_type(8))) short;  // 8 bf16 (4 VGPRs)
using f32x4  = __attribute__((ext_vector_type(4))) float;

#define WSTR 72   // short stride for transposed lo-weight rows (16B multiple)
#define MSTR 68   // uint stride for packed m buffer rows (16B multiple)

__device__ __forceinline__ float silu_f(float v) {
    return v / (1.0f + __expf(-v));
}

// f32 -> bf16 (RNE)
__device__ __forceinline__ short f2bf(float f) {
    unsigned u = __float_as_uint(f);
    unsigned r = (u + 0x7fffu + ((u >> 16) & 1u)) >> 16;
    return (short)r;
}
// bf16 bits -> f32
__device__ __forceinline__ float bf2f(short s) {
    return __uint_as_float(((unsigned)(unsigned short)s) << 16);
}

// register broadcast with compile-time lane (v_readlane)
__device__ __forceinline__ float bcast(float v, int l) {
    return __int_as_float(__builtin_amdgcn_readlane(__float_as_int(v), l));
}

// A = h @ ew1[0:64], B = h @ ew1[64:128]; zero h_neigh / x_neigh for this layer.
__global__ __launch_bounds__(256) void node_pre(
    const float* __restrict__ h, const float* __restrict__ ew1,
    float* __restrict__ A, float* __restrict__ B,
    float* __restrict__ h_neigh, float* __restrict__ x_neigh)
{
    __shared__ float wA[F * F], wB[F * F];
    const int tid = threadIdx.x;
    #pragma unroll 4
    for (int i = tid; i < F * F; i += 256) { wA[i] = ew1[i]; wB[i] = ew1[F * F + i]; }
    __syncthreads();
    const int lane = tid & 63;
    const int nw = gridDim.x * 4;
    const int wid = blockIdx.x * 4 + (tid >> 6);
    for (int g = wid; g < N_NODES / 4; g += nw) {
        const int n0 = g * 4;
        float hr[4];
        #pragma unroll
        for (int e = 0; e < 4; ++e) hr[e] = h[(n0 + e) * F + lane];
        float aA[4] = {0.f, 0.f, 0.f, 0.f}, aB[4] = {0.f, 0.f, 0.f, 0.f};
        #pragma unroll
        for (int k = 0; k < F; ++k) {
            const float wa = wA[k * F + lane];
            const float wb = wB[k * F + lane];
            #pragma unroll
            for (int e = 0; e < 4; ++e) {
                const float hv = bcast(hr[e], k);
                aA[e] = fmaf(hv, wa, aA[e]);
                aB[e] = fmaf(hv, wb, aB[e]);
            }
        }
        #pragma unroll
        for (int e = 0; e < 4; ++e) {
            A[(n0 + e) * F + lane] = aA[e];
            B[(n0 + e) * F + lane] = aB[e];
            h_neigh[(n0 + e) * F + lane] = 0.0f;
        }
        if (lane < 12) x_neigh[n0 * 3 + lane] = 0.0f;
    }
}

// MFMA edge kernel, split-bf16 (hi+lo) for ~f32 accuracy. 16 edges per wave.
// A-frag: [m=lane&15][k=quad*8+j] (+32 per kb). B-frag: [k=quad*8+j][n=lane&15].
// C/D: col=lane&15 (n), row=quad*4+reg (m=edge).
__global__ __launch_bounds__(256) void edge_mfma(
    const float* __restrict__ A, const float* __restrict__ B,
    const float* __restrict__ x,
    const int* __restrict__ src, const int* __restrict__ dst,
    const float* __restrict__ rw,  const float* __restrict__ eb1,
    const float* __restrict__ ew2, const float* __restrict__ eb2,
    const float* __restrict__ cw1, const float* __restrict__ cb1,
    const float* __restrict__ cw2,
    float* __restrict__ h_neigh, float* __restrict__ x_neigh)
{
    __shared__ float rwb[F], eb1b[F];
    __shared__ short wEl[F * WSTR];           // lo(ew2)^T  [n][k]
    __shared__ short wCl[F * WSTR];           // lo(cw1)^T  [n][k]
    __shared__ unsigned mbuf_s[4][16 * MSTR]; // packed (hi<<16|lo) of m, per wave
    __shared__ float cbuf_s[4][16];
    const int tid = threadIdx.x;
    if (tid < 64) rwb[tid] = rw[tid];
    else if (tid < 128) eb1b[tid - 64] = eb1[tid - 64];
    // stage lo residuals of transposed weights
    for (int idx = tid; idx < F * F; idx += 256) {
        const int k = idx >> 6, n = idx & 63;
        const float we = ew2[idx];
        const float wc = cw1[idx];
        wEl[n * WSTR + k] = f2bf(we - bf2f(f2bf(we)));
        wCl[n * WSTR + k] = f2bf(wc - bf2f(f2bf(wc)));
    }
    __syncthreads();
    const int w = tid >> 6, lane = tid & 63;
    const int col = lane & 15, quad = lane >> 4;
    unsigned* mbuf = &mbuf_s[w][0];
    float* cbuf = &cbuf_s[w][0];

    // hi weight B-fragments in registers: index t*2+kb
    short8 wEh[8], wCh[8];
    #pragma unroll
    for (int t = 0; t < 4; ++t)
        #pragma unroll
        for (int kb = 0; kb < 2; ++kb) {
            short8 we, wc;
            #pragma unroll
            for (int j = 0; j < 8; ++j) {
                const int k = kb * 32 + quad * 8 + j;
                we[j] = f2bf(ew2[k * 64 + t * 16 + col]);
                wc[j] = f2bf(cw1[k * 64 + t * 16 + col]);
            }
            wEh[t * 2 + kb] = we; wCh[t * 2 + kb] = wc;
        }
    float eb2c[4], cb1c[4], cw2c[4];
    #pragma unroll
    for (int t = 0; t < 4; ++t) {
        eb2c[t] = eb2[t * 16 + col];
        cb1c[t] = cb1[t * 16 + col];
        cw2c[t] = cw2[t * 16 + col];
    }

    const int eL = lane / 3;                 // coord lanes (<48): edge eL, comp cc
    const int cc = lane - eL * 3;
    const int nw = gridDim.x * 4;
    for (int g = blockIdx.x * 4 + w; g < N_EDGES / 16; g += nw) {
        const int e0 = g * 16;
        const int sv = src[e0 + col];        // edge (col) indices, replicated per quad
        const int dv = dst[e0 + col];

        // gathers directly in A-frag order
        const f32x4* ap = (const f32x4*)(A + (size_t)sv * 64);
        const f32x4* bp = (const f32x4*)(B + (size_t)dv * 64);
        f32x4 ag[4], bg[4];
        ag[0] = ap[quad * 2];     ag[1] = ap[quad * 2 + 1];
        ag[2] = ap[8 + quad * 2]; ag[3] = ap[8 + quad * 2 + 1];
        bg[0] = bp[quad * 2];     bg[1] = bp[quad * 2 + 1];
        bg[2] = bp[8 + quad * 2]; bg[3] = bp[8 + quad * 2 + 1];

        // radial + normalized diff (lanes 0..47 own (edge, comp))
        const int ms = __shfl(sv, eL, 64);
        const int md = __shfl(dv, eL, 64);
        float xs = 0.0f;
        if (lane < 48) xs = x[ms * 3 + cc] - x[md * 3 + cc];
        const float xx = xs * xs;
        const int b3 = col * 3;
        const float radE = __shfl(xx, b3, 64) + __shfl(xx, b3 + 1, 64)
                         + __shfl(xx, b3 + 2, 64);        // radial of edge (col)
        const float rad_e = __shfl(radE, eL, 64);
        const float xdn = xs / (sqrtf(rad_e) + 1e-30f);

        // m1 = silu(A[src]+B[dst]+rad*rw+eb1) -> hi/lo A-frags
        short8 m1h[2], m1l[2];
        const float* agf = (const float*)ag;
        const float* bgf = (const float*)bg;
        #pragma unroll
        for (int kb = 0; kb < 2; ++kb) {
            short8 fh, fl;
            #pragma unroll
            for (int j = 0; j < 8; ++j) {
                const int k = kb * 32 + quad * 8 + j;
                const float pre = agf[kb * 8 + j] + bgf[kb * 8 + j]
                                + radE * rwb[k] + eb1b[k];
                const float v = silu_f(pre);
                const short hi = f2bf(v);
                fh[j] = hi;
                fl[j] = f2bf(v - bf2f(hi));
            }
            m1h[kb] = fh; m1l[kb] = fl;
        }

        // GEMM1: m_pre = m1 @ ew2   (hi*hi + lo*hi + hi*lo)
        f32x4 acc[4];
        #pragma unroll
        for (int t = 0; t < 4; ++t) {
            f32x4 z = {0.f, 0.f, 0.f, 0.f};
            #pragma unroll
            for (int kb = 0; kb < 2; ++kb) {
                const short8 Bl = *(const short8*)&wEl[(t * 16 + col) * WSTR + kb * 32 + quad * 8];
                z = __builtin_amdgcn_mfma_f32_16x16x32_bf16(m1h[kb], wEh[t * 2 + kb], z, 0, 0, 0);
                z = __builtin_amdgcn_mfma_f32_16x16x32_bf16(m1l[kb], wEh[t * 2 + kb], z, 0, 0, 0);
                z = __builtin_amdgcn_mfma_f32_16x16x32_bf16(m1h[kb], Bl, z, 0, 0, 0);
            }
            acc[t] = z;
        }

        // dst of the 4 edges this lane's C/D rows cover
        int dstr[4];
        #pragma unroll
        for (int r = 0; r < 4; ++r) dstr[r] = __shfl(dv, quad * 4 + r, 64);

        // m = silu(m_pre + eb2); scatter h_neigh; stash packed hi/lo m to LDS
        float mval[4][4];
        #pragma unroll
        for (int t = 0; t < 4; ++t)
            #pragma unroll
            for (int r = 0; r < 4; ++r) {
                const float v = silu_f(acc[t][r] + eb2c[t]);
                mval[t][r] = v;
                const short hi = f2bf(v);
                const short lo = f2bf(v - bf2f(hi));
                mbuf[(quad * 4 + r) * MSTR + t * 16 + col] =
                    ((unsigned)(unsigned short)hi << 16) | (unsigned)(unsigned short)lo;
            }
        #pragma unroll
        for (int t = 0; t < 4; ++t)
            #pragma unroll
            for (int r = 0; r < 4; ++r)
                atomicAdd(&h_neigh[(size_t)dstr[r] * 64 + t * 16 + col], mval[t][r]);

        // m as hi/lo A-frags (LDS round trip = C/D -> A layout transform)
        short8 mh[2], ml[2];
        #pragma unroll
        for (int kb = 0; kb < 2; ++kb) {
            const unsigned* mp = &mbuf[col * MSTR + kb * 32 + quad * 8];
            short8 h8, l8;
            #pragma unroll
            for (int j = 0; j < 8; ++j) {
                const unsigned u = mp[j];
                h8[j] = (short)(u >> 16);
                l8[j] = (short)(u & 0xffffu);
            }
            mh[kb] = h8; ml[kb] = l8;
        }

        // GEMM2: c1_pre = m @ cw1   (hi*hi + lo*hi + hi*lo)
        f32x4 acc2[4];
        #pragma unroll
        for (int t = 0; t < 4; ++t) {
            f32x4 z = {0.f, 0.f, 0.f, 0.f};
            #pragma unroll
            for (int kb = 0; kb < 2; ++kb) {
                const short8 Bl = *(const short8*)&wCl[(t * 16 + col) * WSTR + kb * 32 + quad * 8];
                z = __builtin_amdgcn_mfma_f32_16x16x32_bf16(mh[kb], wCh[t * 2 + kb], z, 0, 0, 0);
                z = __builtin_amdgcn_mfma_f32_16x16x32_bf16(ml[kb], wCh[t * 2 + kb], z, 0, 0, 0);
                z = __builtin_amdgcn_mfma_f32_16x16x32_bf16(mh[kb], Bl, z, 0, 0, 0);
            }
            acc2[t] = z;
        }

        // c[e] = sum_f silu(c1_pre + cb1)[e][f] * cw2[f]
        float part[4] = {0.f, 0.f, 0.f, 0.f};
        #pragma unroll
        for (int t = 0; t < 4; ++t)
            #pragma unroll
            for (int r = 0; r < 4; ++r)
                part[r] = fmaf(silu_f(acc2[t][r] + cb1c[t]), cw2c[t], part[r]);
        #pragma unroll
        for (int off = 8; off >= 1; off >>= 1)
            #pragma unroll
            for (int r = 0; r < 4; ++r)
                part[r] += __shfl_xor(part[r], off, 64);

        if (col == 0) {
            f32x4 cv = {part[0], part[1], part[2], part[3]};
            *(f32x4*)&cbuf[quad * 4] = cv;
        }
        if (lane < 48)
            atomicAdd(&x_neigh[(size_t)md * 3 + cc], cbuf[eL] * xdn);
    }
}

// h_new = silu([h,h_neigh] @ nw1 + nb1) @ nw2 + nb2;  x_new = x + x_neigh
__global__ __launch_bounds__(256) void node_post(
    const float* __restrict__ h, const float* __restrict__ hng,
    const float* __restrict__ nw1, const float* __restrict__ nb1,
    const float* __restrict__ nw2, const float* __restrict__ nb2,
    const float* __restrict__ x_in, const float* __restrict__ xng,
    float* __restrict__ h_out, float* __restrict__ x_out)
{
    __shared__ float w1a[F * F], w1b[F * F], w2[F * F];
    const int tid = threadIdx.x;
    #pragma unroll 4
    for (int i = tid; i < F * F; i += 256) {
        w1a[i] = nw1[i]; w1b[i] = nw1[F * F + i]; w2[i] = nw2[i];
    }
    __syncthreads();
    const int lane = tid & 63;
    const float b1 = nb1[lane], b2 = nb2[lane];
    const int nw = gridDim.x * 4;
    const int wid = blockIdx.x * 4 + (tid >> 6);
    for (int g = wid; g < N_NODES / 4; g += nw) {
        const int n0 = g * 4;
        float hr[4], gr[4];
        #pragma unroll
        for (int e = 0; e < 4; ++e) {
            hr[e] = h[(n0 + e) * F + lane];
            gr[e] = hng[(n0 + e) * F + lane];
        }
        float t[4] = {b1, b1, b1, b1};
        #pragma unroll
        for (int k = 0; k < F; ++k) {
            const float wa = w1a[k * F + lane];
            const float wb = w1b[k * F + lane];
            #pragma unroll
            for (int e = 0; e < 4; ++e) {
                t[e] = fmaf(bcast(hr[e], k), wa, t[e]);
                t[e] = fmaf(bcast(gr[e], k), wb, t[e]);
            }
        }
        #pragma unroll
        for (int e = 0; e < 4; ++e) t[e] = silu_f(t[e]);
        float o[4] = {b2, b2, b2, b2};
        #pragma unroll
        for (int k = 0; k < F; ++k) {
            const float wv = w2[k * F + lane];
            #pragma unroll
            for (int e = 0; e < 4; ++e)
                o[e] = fmaf(bcast(t[e], k), wv, o[e]);
        }
        #pragma unroll
        for (int e = 0; e < 4; ++e) h_out[(n0 + e) * F + lane] = o[e];
        if (lane < 12) x_out[n0 * 3 + lane] = x_in[n0 * 3 + lane] + xng[n0 * 3 + lane];
    }
}

extern "C" void kernel_launch(void* const* d_in, const int* in_sizes, int n_in,
                              void* d_out, int out_size, void* d_ws, size_t ws_size,
                              hipStream_t stream) {
    const float* h_in0 = (const float*)d_in[0];
    const float* x_in0 = (const float*)d_in[1];
    const int*   src   = (const int*)d_in[2];
    const int*   dst   = (const int*)d_in[3];
    const float* ew1   = (const float*)d_in[4];
    const float* eb1   = (const float*)d_in[5];
    const float* ew2   = (const float*)d_in[6];
    const float* eb2   = (const float*)d_in[7];
    const float* nw1   = (const float*)d_in[8];
    const float* nb1   = (const float*)d_in[9];
    const float* nw2   = (const float*)d_in[10];
    const float* nb2   = (const float*)d_in[11];
    const float* cw1   = (const float*)d_in[12];
    const float* cb1   = (const float*)d_in[13];
    const float* cw2   = (const float*)d_in[14];
    float* out = (float*)d_out;

    const size_t NF = (size_t)N_NODES * F;
    float* A   = (float*)d_ws;       // [N,64]
    float* Bm  = A + NF;             // [N,64]
    float* hng = Bm + NF;            // h_neigh [N,64]
    float* h0  = hng + NF;           // h ping  [N,64]
    float* h1  = h0 + NF;            // h pong  [N,64]
    float* xw  = h1 + NF;            // x       [N,3]
    float* xng = xw + (size_t)N_NODES * 3;  // x_neigh [N,3]

    for (int d = 0; d < 4; ++d) {
        const float* hcur = (d == 0) ? h_in0 : ((d & 1) ? h0 : h1);
        float* hout = (d & 1) ? h1 : h0;
        const float* xcur = (d == 0) ? x_in0 : xw;
        float* xout = (d == 3) ? out : xw;
        node_pre<<<1024, 256, 0, stream>>>(hcur, ew1 + (size_t)d * 129 * F,
                                           A, Bm, hng, xng);
        edge_mfma<<<1024, 256, 0, stream>>>(A, Bm, xcur, src, dst,
            ew1 + (size_t)d * 129 * F + 128 * F, eb1 + d * F,
            ew2 + (size_t)d * F * F, eb2 + d * F,
            cw1 + (size_t)d * F * F, cb1 + d * F, cw2 + d * F,
            hng, xng);
        node_post<<<768, 256, 0, stream>>>(hcur, hng,
            nw1 + (size_t)d * 2 * F * F, nb1 + d * F,
            nw2 + (size_t)d * F * F, nb2 + d * F,
            xcur, xng, hout, xout);
    }
}